// Round 14
// baseline (454.212 us; speedup 1.0000x reference)
//
#include <hip/hip_runtime.h>

#define HSZ 64
#define ISZ 8
#define TSZ 512
#define BTILE 16   // batch rows per block
#define NW 16      // waves per block (1024 threads) -> 4 waves/SIMD
#define KP 72      // u16 per row: [0,64) h + 8 pad; 144 B row stride

typedef _Float16 f16;
typedef __attribute__((ext_vector_type(8))) _Float16 f16x8;
typedef __attribute__((ext_vector_type(4))) float f32x4;
typedef unsigned short u16;

__device__ __forceinline__ u16 f16bits(float f) {
    union { f16 h; u16 u; } v; v.h = (f16)f;
    return v.u;
}

// r9 geometry + reg-resident x + drain-free barrier.
// Operand-swapped MFMA: A = weights (M = 16 gate rows, gc = gate*64+4w+(lr>>2)),
// B = h (LDS) / x (registers), N = 16 batch. Lane (lr,lg) holds all 4 gates of
// unit (batch lr, hidden 4w+lg) in acc[0..3] -> act lane-local. Bias = MFMA C-in,
// pre-scaled by -log2e / -2log2e. x never touches LDS: each lane loads row lr
// from global (dup lanes L1-broadcast), converts to f16x8; wa2 is zero for
// lg>=1 so garbage B-slices contribute exactly 0.
// KEY: the loop barrier is raw s_barrier with lgkmcnt(0)-only wait -- no
// vmcnt(0) drain, so the x prefetch stays in flight ACROSS the barrier
// (__syncthreads would drain it every step, exposing ~200cyc L2 latency).
__global__ __launch_bounds__(1024, 4) void lstm_w16c(
    const float* __restrict__ x,      // [B, T, I]
    const float* __restrict__ W_ih,   // [4H, I]
    const float* __restrict__ W_hh,   // [4H, H]
    const float* __restrict__ b_ih,   // [4H]
    const float* __restrict__ b_hh,   // [4H]
    const float* __restrict__ W_fc,   // [O, H]
    const float* __restrict__ b_fc,   // [O]
    float* __restrict__ out)          // [B, O]
{
    const int tid = threadIdx.x;
    const int w  = tid >> 6;          // wave 0..15, owns hidden units [4w, 4w+4)
    const int l  = tid & 63;
    const int lr = l & 15;            // A: M-row sel / B,C: batch col
    const int lg = l >> 4;            // k-group; act: hidden unit 4w+lg
    const int B0 = blockIdx.x * BTILE;
    const int hcol = 4 * w + lg;      // this lane's hidden unit

    __shared__ __align__(16) u16 H[2][BTILE][KP];  // [buf][batch row][k(h)]
    __shared__ float red[NW][BTILE];

    for (int i = tid; i < 2 * BTILE * KP; i += 1024)
        ((u16*)H)[i] = 0;

    // ---- A-fragments (weights), pre-scaled; bias as C-in ----
    const int gate = lr & 3;
    const int gc   = gate * HSZ + 4 * w + (lr >> 2);   // gate row in [0,256)
    const float sc = (gate == 2) ? -2.885390082f : -1.442695041f;
    f16x8 wa0, wa1, wa2;
    {
        const float4 a = *reinterpret_cast<const float4*>(&W_hh[gc * HSZ + lg * 8]);
        const float4 b = *reinterpret_cast<const float4*>(&W_hh[gc * HSZ + lg * 8 + 4]);
        wa0[0] = (f16)(sc * a.x); wa0[1] = (f16)(sc * a.y);
        wa0[2] = (f16)(sc * a.z); wa0[3] = (f16)(sc * a.w);
        wa0[4] = (f16)(sc * b.x); wa0[5] = (f16)(sc * b.y);
        wa0[6] = (f16)(sc * b.z); wa0[7] = (f16)(sc * b.w);
    }
    {
        const float4 a = *reinterpret_cast<const float4*>(&W_hh[gc * HSZ + 32 + lg * 8]);
        const float4 b = *reinterpret_cast<const float4*>(&W_hh[gc * HSZ + 32 + lg * 8 + 4]);
        wa1[0] = (f16)(sc * a.x); wa1[1] = (f16)(sc * a.y);
        wa1[2] = (f16)(sc * a.z); wa1[3] = (f16)(sc * a.w);
        wa1[4] = (f16)(sc * b.x); wa1[5] = (f16)(sc * b.y);
        wa1[6] = (f16)(sc * b.z); wa1[7] = (f16)(sc * b.w);
    }
#pragma unroll
    for (int j = 0; j < 8; ++j) wa2[j] = (f16)0.0f;
    if (lg == 0) {                    // x-MFMA k-slice [0,8) = W_ih; rest zero
        const float4 a = *reinterpret_cast<const float4*>(&W_ih[gc * ISZ]);
        const float4 b = *reinterpret_cast<const float4*>(&W_ih[gc * ISZ + 4]);
        wa2[0] = (f16)(sc * a.x); wa2[1] = (f16)(sc * a.y);
        wa2[2] = (f16)(sc * a.z); wa2[3] = (f16)(sc * a.w);
        wa2[4] = (f16)(sc * b.x); wa2[5] = (f16)(sc * b.y);
        wa2[6] = (f16)(sc * b.z); wa2[7] = (f16)(sc * b.w);
    }

    // per-lane bias vector (C-in of the x-MFMA): gate r of unit hcol
    f32x4 bias4;
#pragma unroll
    for (int r = 0; r < 4; ++r) {
        const float s = (r == 2) ? -2.885390082f : -1.442695041f;
        bias4[r] = s * (b_ih[r * HSZ + hcol] + b_hh[r * HSZ + hcol]);
    }

    __syncthreads();  // zeroing visible (h(0)=0 in both buffers)

    // hoisted LDS offsets (u16 units)
    const u16* rd0 = &H[0][lr][lg * 8];
    const u16* rd1 = &H[1][lr][lg * 8];
    u16* wr0 = &H[0][lr][hcol];
    u16* wr1 = &H[1][lr][hcol];

    // x: every lane loads batch row lr (4 lanes/wave dup -> L1 broadcast)
    const float* xrow = x + (size_t)(B0 + lr) * TSZ * ISZ;
    float4 xa = *reinterpret_cast<const float4*>(xrow);
    float4 xb = *reinterpret_cast<const float4*>(xrow + 4);

    float c = 0.0f, h = 0.0f;
    const float L2 = 2.885390082f;

#define STEP(RD, WR, T, GUARD)                                                 \
    {                                                                          \
        f16x8 b2;                                                              \
        b2[0] = (f16)xa.x; b2[1] = (f16)xa.y; b2[2] = (f16)xa.z;               \
        b2[3] = (f16)xa.w; b2[4] = (f16)xb.x; b2[5] = (f16)xb.y;               \
        b2[6] = (f16)xb.z; b2[7] = (f16)xb.w;                                  \
        if (GUARD) {  /* prefetch x(T+1); stays in flight across the barrier */\
            xa = *reinterpret_cast<const float4*>(xrow + (size_t)(T + 1) * ISZ);     \
            xb = *reinterpret_cast<const float4*>(xrow + (size_t)(T + 1) * ISZ + 4); \
        }                                                                      \
        const f16x8 b0 = *reinterpret_cast<const f16x8*>(RD);                  \
        const f16x8 b1 = *reinterpret_cast<const f16x8*>(RD + 32);             \
        f32x4 acc = __builtin_amdgcn_mfma_f32_16x16x32_f16(wa2, b2, bias4, 0, 0, 0); \
        acc = __builtin_amdgcn_mfma_f32_16x16x32_f16(wa0, b0, acc, 0, 0, 0);   \
        acc = __builtin_amdgcn_mfma_f32_16x16x32_f16(wa1, b1, acc, 0, 0, 0);   \
        const float ea = __builtin_amdgcn_exp2f(acc[0]);                       \
        const float eb = __builtin_amdgcn_exp2f(acc[1]);                       \
        const float ed = __builtin_amdgcn_exp2f(acc[2]);                       \
        const float es = __builtin_amdgcn_exp2f(acc[3]);                       \
        const float A1 = 1.0f + ea, B1 = 1.0f + eb, D1 = 1.0f + ed;            \
        const float R1 = __builtin_amdgcn_rcpf(A1 * B1 * D1);                  \
        c = fmaf(c * A1, D1, (1.0f - ed) * B1) * R1;                           \
        const float eu = __builtin_amdgcn_exp2f(-L2 * c);                      \
        const float R2 = __builtin_amdgcn_rcpf((1.0f + es) * (1.0f + eu));     \
        h = (1.0f - eu) * R2;                                                  \
        *(WR) = f16bits(h);                                                    \
        /* drain-free barrier: order my ds_write (lgkm only), NOT the x load */\
        asm volatile("s_waitcnt lgkmcnt(0)" ::: "memory");                     \
        __builtin_amdgcn_s_barrier();                                          \
        asm volatile("" ::: "memory");                                         \
        __builtin_amdgcn_sched_barrier(0);                                     \
    }

    for (int t = 0; t < TSZ; t += 2) {
        // step t: read buf0, write h into buf1. x(t+1) always exists (t+1<=511).
        STEP(rd0, wr1, t, true)
        // step t+1: read buf1, write into buf0. x(t+2) exists unless t == 510.
        STEP(rd1, wr0, t + 1, t < TSZ - 2)
    }
#undef STEP

    // ---- final FC: out[b] = sum_h h(b,hu) * W_fc[hu] + b_fc ----
    float v = h * W_fc[hcol];
    v += __shfl_xor(v, 16);
    v += __shfl_xor(v, 32);           // sum over lg: wave-partial per batch row lr
    if (lg == 0) red[w][lr] = v;
    __syncthreads();
    if (tid < BTILE) {
        float s = b_fc[0];
#pragma unroll
        for (int ww = 0; ww < NW; ++ww) s += red[ww][tid];
        out[B0 + tid] = s;
    }
}

extern "C" void kernel_launch(void* const* d_in, const int* in_sizes, int n_in,
                              void* d_out, int out_size, void* d_ws, size_t ws_size,
                              hipStream_t stream) {
    const float* x    = (const float*)d_in[0];
    const float* W_ih = (const float*)d_in[1];
    const float* W_hh = (const float*)d_in[2];
    const float* b_ih = (const float*)d_in[3];
    const float* b_hh = (const float*)d_in[4];
    const float* W_fc = (const float*)d_in[5];
    const float* b_fc = (const float*)d_in[6];
    float* out = (float*)d_out;

    const int B = in_sizes[0] / (TSZ * ISZ);  // 4096
    lstm_w16c<<<B / BTILE, NW * 64, 0, stream>>>(x, W_ih, W_hh, b_ih, b_hh, W_fc, b_fc, out);
}